// Round 4
// baseline (201.167 us; speedup 1.0000x reference)
//
#include <hip/hip_runtime.h>
#include <math.h>

#define HH 1024
#define WW 1024
#define NPLANES 12              // B*C = 4*3
#define PLANE (HH * WW)

#define TW 64                   // output tile width
#define TH 64                   // output tile height
#define RH 92                   // h1 rows: gy in [y0-14, y0+77]  (phys rows 0..91)
#define RB 78                   // B1/h2 logical rows: gy in [y0-7, y0+70]
#define PH 80                   // pitch (floats), 20 quads, quad-XOR swizzle by (physrow & 3)
// LDS: phys rows 0..91 = h1 (later h2 in rows 0..77); B1 logical rows 0..63 at
// phys rows 92..155; B1 logical rows 64..77 ALIAS h1 phys rows 78..91 (their
// last use is the same P3 iteration that produces the aliasing write).
#define LDSF (156 * PH)         // 49,920 B -> 50,176 alloc -> 3 blocks/CU

struct W15 { float w[15]; };

__device__ inline float chain1(float t, float gain, float gamma, float sb,
                               float hr, float br, float ct) {
    t = t * gain;
    t = __builtin_amdgcn_exp2f(gamma * __log2f(t));          // pow(t,gamma), t>=0
    float hi = __fdividef(1.0f, 1.0f + __expf((0.5f - t) * 10.0f));
    t = t + sb * (1.0f - hi) - hr * hi;
    t = fminf(fmaxf(t, 0.0f), 1.0f);
    t = ct * (t - 0.5f) + 0.5f + br;
    return fminf(fmaxf(t, 0.0f), 1.0f);
}

// B1 logical row -> physical LDS row
__device__ inline int b1r(int r) { return (r < 64) ? (92 + r) : (r + 14); }
// swizzled addressing (quad q of phys row pr stored at quad q ^ (pr&3))
__device__ inline int swq(int pr, int q) { return pr * PH + ((q ^ (pr & 3)) << 2); }
__device__ inline int sws(int pr, int j) {
    return pr * PH + ((((j >> 2) ^ (pr & 3)) << 2) | (j & 3));
}

// 16 outputs from a 32-float register window; output j taps f[j+1 .. j+15]
__device__ inline void dot16(const float* f, const W15& wk, float* o) {
#pragma unroll
    for (int j = 0; j < 16; ++j) {
        float a = 0.0f, b = 0.0f;
#pragma unroll
        for (int k = 0; k < 8; ++k)  a += wk.w[k] * f[j + 1 + k];
#pragma unroll
        for (int k = 8; k < 15; ++k) b += wk.w[k] * f[j + 1 + k];
        o[j] = a + b;
    }
}

__device__ inline float dot15(const float* win, const W15& wk) {
    float a = 0.0f, b = 0.0f;
#pragma unroll
    for (int k = 0; k < 8; ++k)  a += wk.w[k] * win[k];
#pragma unroll
    for (int k = 8; k < 15; ++k) b += wk.w[k] * win[k];
    return a + b;
}

// ---- XCD-aware tile remap: same-XCD (mod-8) blocks cover contiguous region ---
__device__ inline void tile_map(int& p, int& x0, int& y0, bool& edge) {
    int L = (blockIdx.z * gridDim.y + blockIdx.y) * gridDim.x + blockIdx.x; // 0..3071
    int xcd = L & 7;
    int t   = L >> 3;
    int g   = xcd * 384 + t;          // contiguous 1.5-plane region per XCD
    p = g >> 8;
    int w  = g & 255;
    int ty = w >> 4, tx = w & 15;
    x0 = tx * TW; y0 = ty * TH;
    edge = (tx == 0) || (tx == 15) || (ty == 0) || (ty == 15);
}

// =============================================================================
// Single fused kernel:
//  P1: h1 = hblur(chain(x))  global->regs->LDS rows 0..91
//      (16-aligned windows: every quad fully in/out of image -> vector edge path)
//  cc: chain(x) at tile centers (coalesced loads, overlaps barrier)
//  P3: B1 = vblur(h1) masked to image; tail rows alias h1 rows 78..91
//  P4: h2 = hblur(B1) -> LDS rows 0..77
//  P5: B2 = vblur(h2); x2c=(1+e)cc-e*bb; bx2=(1+e)bb-e*B2;
//      out = clip((s*bx2+(1-s)*x2c)*(1-intensity*mask))
// =============================================================================
__global__ __launch_bounds__(256, 3) void k_fused(
    const float* __restrict__ x, float* __restrict__ dst,
    const float* __restrict__ gains,
    const float* __restrict__ pg, const float* __restrict__ psb,
    const float* __restrict__ phr, const float* __restrict__ pbr,
    const float* __restrict__ pct, const float* __restrict__ penh,
    const float* __restrict__ psoft, const float* __restrict__ pint,
    const float* __restrict__ prot, const float* __restrict__ phard,
    W15 wk)
{
    __shared__ float lds[LDSF];

    int p, x0, y0; bool edge;
    tile_map(p, x0, y0, edge);
    const int tid = threadIdx.x;
    const int tx  = tid & 63;
    const int ty  = tid >> 6;

    const float* __restrict__ plane = x + (size_t)p * PLANE;
    const float gain  = gains[p % 3];
    const float gamma = *pg, sb = *psb, hr = *phr, br = *pbr, ct = *pct;

    // ---------------- P1: h1 rows; chain applied in-register ------------------
    // unit u -> row r = u/5 (gy = y0-14+r), seg s (out cols gx = x0-8+16s+j)
#pragma unroll
    for (int it = 0; it < 2; ++it) {
        int u = tid + 256 * it;
        if (u < RH * 5) {
            int r = u / 5, s = u - 5 * r;
            int gy  = y0 - 14 + r;
            int gxa = x0 + 16 * s - 16;          // 16-aligned window base
            float o[16];
            bool rowin = (unsigned)gy < HH;      // edge tiles only can be false
            if (!edge) {
                const float* rp = plane + (size_t)gy * WW + gxa;
                float f[32];
#pragma unroll
                for (int i = 0; i < 8; ++i)
                    *(float4*)&f[4 * i] = *(const float4*)(rp + 4 * i);
#pragma unroll
                for (int e2 = 1; e2 < 31; ++e2)   // f[0], f[31] never tapped
                    f[e2] = chain1(f[e2], gain, gamma, sb, hr, br, ct);
                dot16(f, wk, o);
            } else if (rowin) {
                const float* rp = plane + (size_t)gy * WW;
                float f[32];
#pragma unroll
                for (int i = 0; i < 8; ++i) {
                    int gq = gxa + 4 * i;
                    float4 v = make_float4(0.f, 0.f, 0.f, 0.f);
                    if (gq >= 0 && gq + 3 < WW) {       // quads are all-in or all-out
                        v = *(const float4*)(rp + gq);
                        float* pv = (float*)&v;
#pragma unroll
                        for (int q2 = 0; q2 < 4; ++q2)
                            pv[q2] = chain1(pv[q2], gain, gamma, sb, hr, br, ct);
                    }
                    *(float4*)&f[4 * i] = v;
                }
                dot16(f, wk, o);
            } else {
#pragma unroll
                for (int j = 0; j < 16; ++j) o[j] = 0.0f;
            }
#pragma unroll
            for (int qq = 0; qq < 4; ++qq)
                *(float4*)&lds[swq(r, 4 * s + qq)] = *(float4*)&o[4 * qq];
        }
    }

    // ---------------- cc: chain(x) at centers (overlaps barrier wait) ---------
    float cc[16];
    {
        const float* pc0 = plane + (size_t)(y0 + ty * 16) * WW + (x0 + tx);
#pragma unroll
        for (int jj = 0; jj < 16; ++jj) cc[jj] = pc0[(size_t)jj * WW];
#pragma unroll
        for (int jj = 0; jj < 16; ++jj)
            cc[jj] = chain1(cc[jj], gain, gamma, sb, hr, br, ct);
    }
    __syncthreads();

    // ---------------- P3: B1 = vblur(h1), masked to image support -------------
    if (tid < 240) {
        int j = tid % 80, band = tid / 80;
        int rb0 = band * 28;                     // 0, 28, 56
        int nj  = (band == 2) ? 22 : 28;         // 28+28+22 = 78 rows
        bool xin = (unsigned)(x0 - 8 + j) < WW;
        float win[15];
#pragma unroll
        for (int k = 0; k < 14; ++k) win[k] = lds[sws(rb0 + k, j)];
#pragma unroll
        for (int jj = 0; jj < 28; ++jj) {
            if (jj < nj) {
                int rl = rb0 + jj;               // logical B1 row
                win[14] = lds[sws(rl + 14, j)];
                float v = dot15(win, wk);
                if (edge) {
                    int gy = y0 - 7 + rl;
                    if (!((unsigned)gy < HH) || !xin) v = 0.0f;
                }
                // for rl>=64 this address == the win[14] address just read
                lds[sws(b1r(rl), j)] = v;
#pragma unroll
                for (int k = 0; k < 14; ++k) win[k] = win[k + 1];
            }
        }
    }
    __syncthreads();

    // ---------------- P4: h2 = hblur(B1) -> rows 0..77, quads 0..15 -----------
#pragma unroll
    for (int it = 0; it < 2; ++it) {
        int u = tid + 256 * it;
        if (u < RB * 4) {
            int rb = u >> 2, s = u & 3;          // out cols gx = x0 + 16s + j
            int pb = b1r(rb);
            float f[32];
#pragma unroll
            for (int i = 0; i < 8; ++i)
                *(float4*)&f[4 * i] = *(const float4*)&lds[swq(pb, 4 * s + i)];
            float o[16];
            dot16(f, wk, o);
#pragma unroll
            for (int qq = 0; qq < 4; ++qq)
                *(float4*)&lds[swq(rb, 4 * s + qq)] = *(float4*)&o[4 * qq];
        }
    }
    __syncthreads();

    // ---------------- P5: B2 = vblur(h2); combine + mask + clip + store -------
    const float e     = *penh;
    const float sf    = *psoft;
    const float inten = *pint;
    const float hard  = *phard;
    const float theta = (*prot) * 0.017453292519943295f;
    const float cth = __cosf(theta), sth = __sinf(theta);
    const int   gx    = x0 + tx;
    const float gbase = (-1.0f + 2.0f * (float)gx * (1.0f / (float)(WW - 1))) * cth;
    const float ce    = 1.0f + e;

    float bb[16];
#pragma unroll
    for (int jj = 0; jj < 16; ++jj)
        bb[jj] = lds[sws(b1r(ty * 16 + jj + 7), tx + 8)];

    float win[15];
#pragma unroll
    for (int k = 0; k < 14; ++k) win[k] = lds[sws(ty * 16 + k, tx)];

    float* __restrict__ dstP = dst + (size_t)p * PLANE;
#pragma unroll
    for (int jj = 0; jj < 16; ++jj) {
        win[14] = lds[sws(ty * 16 + jj + 14, tx)];
        float B2  = dot15(win, wk);
        float x2c = ce * cc[jj] - e * bb[jj];       // x2 at center
        float bx2 = ce * bb[jj] - e * B2;           // blur(x2) via linearity
        float v   = sf * bx2 + (1.0f - sf) * x2c;
        int   y   = y0 + ty * 16 + jj;
        float gyn = -1.0f + 2.0f * (float)y * (1.0f / (float)(HH - 1));
        float mask = __fdividef(1.0f, 1.0f + __expf(hard * (gbase + gyn * sth)));
        v = v * (1.0f - inten * mask);
        v = fminf(fmaxf(v, 0.0f), 1.0f);
        dstP[(size_t)y * WW + gx] = v;
#pragma unroll
        for (int k = 0; k < 14; ++k) win[k] = win[k + 1];
    }
}

extern "C" void kernel_launch(void* const* d_in, const int* in_sizes, int n_in,
                              void* d_out, int out_size, void* d_ws, size_t ws_size,
                              hipStream_t stream)
{
    const float* x       = (const float*)d_in[0];
    const float* gains   = (const float*)d_in[1];
    const float* p_gamma = (const float*)d_in[2];
    const float* p_sb    = (const float*)d_in[3];
    const float* p_hr    = (const float*)d_in[4];
    const float* p_br    = (const float*)d_in[5];
    const float* p_ct    = (const float*)d_in[6];
    const float* p_enh   = (const float*)d_in[7];
    const float* p_soft  = (const float*)d_in[8];
    const float* p_int   = (const float*)d_in[9];
    const float* p_rot   = (const float*)d_in[10];
    const float* p_hard  = (const float*)d_in[11];

    W15 wk;
    {
        double g[15], sum = 0.0;
        for (int i = 0; i < 15; ++i) { double d = (double)(i - 7); g[i] = exp(-d * d / 18.0); sum += g[i]; }
        for (int i = 0; i < 15; ++i) wk.w[i] = (float)(g[i] / sum);
    }

    dim3 grid(WW / TW, HH / TH, NPLANES);   // 16 x 16 x 12 (remapped in-kernel)
    k_fused<<<grid, dim3(256), 0, stream>>>(
        x, (float*)d_out, gains, p_gamma, p_sb, p_hr, p_br, p_ct,
        p_enh, p_soft, p_int, p_rot, p_hard, wk);
}

// Round 5
// 183.023 us; speedup vs baseline: 1.0991x; 1.0991x over previous
//
#include <hip/hip_runtime.h>
#include <math.h>

#define HH 1024
#define WW 1024
#define NPLANES 12              // B*C = 4*3
#define PLANE (HH * WW)
#define NTOT (NPLANES * PLANE)

#define TW 64                   // output tile width
#define TH 64                   // output tile height
#define RH 92                   // h1 rows: gy in [y0-14, y0+77]  (phys rows 0..91)
#define RB 78                   // B1/h2 logical rows: gy in [y0-7, y0+70]
#define PH 80                   // pitch (floats), 20 quads, quad-XOR swizzle by (physrow & 3)
// LDS: phys rows 0..91 = h1 (later h2 in rows 0..77); B1 logical rows 0..63 at
// phys rows 92..155; B1 logical rows 64..77 ALIAS h1 phys rows 78..91 (their
// last use is the same P3 iteration that produces the aliasing write).
#define LDSF (156 * PH)         // 49,920 B -> 50,176 alloc -> 3 blocks/CU

typedef float vf4 __attribute__((ext_vector_type(4)));

struct W15 { float w[15]; };

__device__ inline float chain1(float t, float gain, float gamma, float sb,
                               float hr, float br, float ct) {
    t = t * gain;
    t = __builtin_amdgcn_exp2f(gamma * __log2f(t));          // pow(t,gamma), t>=0
    float hi = __fdividef(1.0f, 1.0f + __expf((0.5f - t) * 10.0f));
    t = t + sb * (1.0f - hi) - hr * hi;
    t = fminf(fmaxf(t, 0.0f), 1.0f);
    t = ct * (t - 0.5f) + 0.5f + br;
    return fminf(fmaxf(t, 0.0f), 1.0f);
}

// B1 logical row -> physical LDS row
__device__ inline int b1r(int r) { return (r < 64) ? (92 + r) : (r + 14); }
// swizzled addressing (quad q of phys row pr stored at quad q ^ (pr&3))
__device__ inline int swq(int pr, int q) { return pr * PH + ((q ^ (pr & 3)) << 2); }
__device__ inline int sws(int pr, int j) {
    return pr * PH + ((((j >> 2) ^ (pr & 3)) << 2) | (j & 3));
}

// 16 outputs from a 32-float register window; output j taps f[j+1 .. j+15]
__device__ inline void dot16(const float* f, const W15& wk, float* o) {
#pragma unroll
    for (int j = 0; j < 16; ++j) {
        float a = 0.0f, b = 0.0f;
#pragma unroll
        for (int k = 0; k < 8; ++k)  a += wk.w[k] * f[j + 1 + k];
#pragma unroll
        for (int k = 8; k < 15; ++k) b += wk.w[k] * f[j + 1 + k];
        o[j] = a + b;
    }
}

__device__ inline float dot15(const float* win, const W15& wk) {
    float a = 0.0f, b = 0.0f;
#pragma unroll
    for (int k = 0; k < 8; ++k)  a += wk.w[k] * win[k];
#pragma unroll
    for (int k = 8; k < 15; ++k) b += wk.w[k] * win[k];
    return a + b;
}

// ---- XCD-aware tile remap: same-XCD (mod-8) blocks cover contiguous region ---
__device__ inline void tile_map(int& p, int& x0, int& y0, bool& edge) {
    int L = (blockIdx.z * gridDim.y + blockIdx.y) * gridDim.x + blockIdx.x; // 0..3071
    int xcd = L & 7;
    int t   = L >> 3;
    int g   = xcd * 384 + t;          // contiguous 1.5-plane region per XCD
    p = g >> 8;
    int w  = g & 255;
    int ty = w >> 4, tx = w & 15;
    x0 = tx * TW; y0 = ty * TH;
    edge = (tx == 0) || (tx == 15) || (ty == 0) || (ty == 15);
}

// ============ K1: pointwise chain, x -> x1 ====================================
// 32B/thread; nontemporal loads (x is read-once -> don't evict X1 from L2/L3).
__global__ __launch_bounds__(256) void k_point(
    const vf4* __restrict__ x, vf4* __restrict__ o,
    const float* __restrict__ gains,
    const float* __restrict__ pg, const float* __restrict__ psb,
    const float* __restrict__ phr, const float* __restrict__ pbr,
    const float* __restrict__ pct)
{
    int i = blockIdx.x * blockDim.x + threadIdx.x;   // 0 .. NTOT/8-1
    int c = ((i * 8) / PLANE) % 3;                   // PLANE % 8 == 0 -> uniform
    float gain = gains[c];
    float gamma = *pg, sb = *psb, hr = *phr, br = *pbr, ct = *pct;

    vf4 v0 = __builtin_nontemporal_load(x + 2 * i);
    vf4 v1 = __builtin_nontemporal_load(x + 2 * i + 1);
#pragma unroll
    for (int j = 0; j < 4; ++j) {
        v0[j] = chain1(v0[j], gain, gamma, sb, hr, br, ct);
        v1[j] = chain1(v1[j], gain, gamma, sb, hr, br, ct);
    }
    o[2 * i]     = v0;
    o[2 * i + 1] = v1;
}

// ============ K2: double blur from x1 (global) + combine + mask ===============
//  P1: h1 = hblur(x1) global->regs->LDS rows 0..91
//  cc: x1 at tile centers (plain loads, overlap barrier)
//  P3: B1 = vblur(h1) masked to image; tail rows alias h1 rows 78..91
//  P4: h2 = hblur(B1) -> LDS rows 0..77
//  P5: B2 = vblur(h2); x2c=(1+e)cc-e*bb; bx2=(1+e)bb-e*B2;
//      out = clip((s*bx2+(1-s)*x2c)*(1-intensity*mask))
// =============================================================================
__global__ __launch_bounds__(256, 3) void k_fused(
    const float* __restrict__ x1, float* __restrict__ dst,
    const float* __restrict__ penh,
    const float* __restrict__ psoft, const float* __restrict__ pint,
    const float* __restrict__ prot, const float* __restrict__ phard,
    W15 wk)
{
    __shared__ float lds[LDSF];

    int p, x0, y0; bool edge;
    tile_map(p, x0, y0, edge);
    const int tid = threadIdx.x;
    const int tx  = tid & 63;
    const int ty  = tid >> 6;

    const float* __restrict__ plane = x1 + (size_t)p * PLANE;

    // ---------------- P1: h1 rows straight from global x1 ---------------------
    // unit u -> row r = u/5 (gy = y0-14+r), seg s (out cols gx = x0-8+16s+j)
#pragma unroll
    for (int it = 0; it < 2; ++it) {
        int u = tid + 256 * it;
        if (u < RH * 5) {
            int r = u / 5, s = u - 5 * r;
            int gy  = y0 - 14 + r;
            int gxa = x0 + 16 * s - 16;          // 16-aligned window base
            float f[32];
            if (!edge) {
                const float* rp = plane + (size_t)gy * WW + gxa;
#pragma unroll
                for (int i = 0; i < 8; ++i)
                    *(float4*)&f[4 * i] = *(const float4*)(rp + 4 * i);
            } else {
                bool rowin = (unsigned)gy < HH;
                const float* rp = plane + (size_t)(rowin ? gy : 0) * WW;
#pragma unroll
                for (int i = 0; i < 8; ++i) {
                    int gq = gxa + 4 * i;
                    float4 v = make_float4(0.f, 0.f, 0.f, 0.f);
                    if (rowin && gq >= 0 && gq + 3 < WW)   // quads all-in or all-out
                        v = *(const float4*)(rp + gq);
                    *(float4*)&f[4 * i] = v;
                }
            }
            float o[16];
            dot16(f, wk, o);
#pragma unroll
            for (int qq = 0; qq < 4; ++qq)
                *(float4*)&lds[swq(r, 4 * s + qq)] = *(float4*)&o[4 * qq];
        }
    }

    // ---------------- cc: x1 at centers (global; overlaps barrier wait) -------
    float cc[16];
    {
        const float* pc0 = plane + (size_t)(y0 + ty * 16) * WW + (x0 + tx);
#pragma unroll
        for (int jj = 0; jj < 16; ++jj) cc[jj] = pc0[(size_t)jj * WW];
    }
    __syncthreads();

    // ---------------- P3: B1 = vblur(h1), masked to image support -------------
    // uniform 26-row bands (alias-safe: band1 reads <= row 65 < 78; band2's
    // writes to phys 78..91 are same-thread read-then-write of that row)
    if (tid < 240) {
        int j = tid % 80, band = tid / 80;
        int rb0 = band * 26;                     // 0, 26, 52
        bool xin = (unsigned)(x0 - 8 + j) < WW;
        float win[15];
#pragma unroll
        for (int k = 0; k < 14; ++k) win[k] = lds[sws(rb0 + k, j)];
#pragma unroll
        for (int jj = 0; jj < 26; ++jj) {
            int rl = rb0 + jj;                   // logical B1 row
            win[14] = lds[sws(rl + 14, j)];
            float v = dot15(win, wk);
            if (edge) {
                int gy = y0 - 7 + rl;
                if (!((unsigned)gy < HH) || !xin) v = 0.0f;
            }
            lds[sws(b1r(rl), j)] = v;
#pragma unroll
            for (int k = 0; k < 14; ++k) win[k] = win[k + 1];
        }
    }
    __syncthreads();

    // ---------------- P4: h2 = hblur(B1) -> rows 0..77, quads 0..15 -----------
#pragma unroll
    for (int it = 0; it < 2; ++it) {
        int u = tid + 256 * it;
        if (u < RB * 4) {
            int rb = u >> 2, s = u & 3;          // out cols gx = x0 + 16s + j
            int pb = b1r(rb);
            float f[32];
#pragma unroll
            for (int i = 0; i < 8; ++i)
                *(float4*)&f[4 * i] = *(const float4*)&lds[swq(pb, 4 * s + i)];
            float o[16];
            dot16(f, wk, o);
#pragma unroll
            for (int qq = 0; qq < 4; ++qq)
                *(float4*)&lds[swq(rb, 4 * s + qq)] = *(float4*)&o[4 * qq];
        }
    }
    __syncthreads();

    // ---------------- P5: B2 = vblur(h2); combine + mask + clip + store -------
    const float e     = *penh;
    const float sf    = *psoft;
    const float inten = *pint;
    const float hard  = *phard;
    const float theta = (*prot) * 0.017453292519943295f;
    const float cth = __cosf(theta), sth = __sinf(theta);
    const int   gx    = x0 + tx;
    const float gbase = (-1.0f + 2.0f * (float)gx * (1.0f / (float)(WW - 1))) * cth;
    const float ce    = 1.0f + e;

    // gradient-mask exp is linear in y -> geometric recurrence (1 exp, 15 muls)
    const float dstep = 2.0f / (float)(HH - 1);
    const float gy0n  = -1.0f + (float)(y0 + ty * 16) * dstep;
    float       E     = __expf(hard * (gbase + gy0n * sth));
    const float q     = __expf(hard * sth * dstep);

    float bb[16];
#pragma unroll
    for (int jj = 0; jj < 16; ++jj)
        bb[jj] = lds[sws(b1r(ty * 16 + jj + 7), tx + 8)];

    float win[15];
#pragma unroll
    for (int k = 0; k < 14; ++k) win[k] = lds[sws(ty * 16 + k, tx)];

    float* __restrict__ dstP = dst + (size_t)p * PLANE;
#pragma unroll
    for (int jj = 0; jj < 16; ++jj) {
        win[14] = lds[sws(ty * 16 + jj + 14, tx)];
        float B2  = dot15(win, wk);
        float x2c = ce * cc[jj] - e * bb[jj];       // x2 at center
        float bx2 = ce * bb[jj] - e * B2;           // blur(x2) via linearity
        float v   = sf * bx2 + (1.0f - sf) * x2c;
        int   y   = y0 + ty * 16 + jj;
        float mask = __fdividef(1.0f, 1.0f + E);
        E *= q;
        v = v * (1.0f - inten * mask);
        v = fminf(fmaxf(v, 0.0f), 1.0f);
        dstP[(size_t)y * WW + gx] = v;
#pragma unroll
        for (int k = 0; k < 14; ++k) win[k] = win[k + 1];
    }
}

extern "C" void kernel_launch(void* const* d_in, const int* in_sizes, int n_in,
                              void* d_out, int out_size, void* d_ws, size_t ws_size,
                              hipStream_t stream)
{
    const float* x       = (const float*)d_in[0];
    const float* gains   = (const float*)d_in[1];
    const float* p_gamma = (const float*)d_in[2];
    const float* p_sb    = (const float*)d_in[3];
    const float* p_hr    = (const float*)d_in[4];
    const float* p_br    = (const float*)d_in[5];
    const float* p_ct    = (const float*)d_in[6];
    const float* p_enh   = (const float*)d_in[7];
    const float* p_soft  = (const float*)d_in[8];
    const float* p_int   = (const float*)d_in[9];
    const float* p_rot   = (const float*)d_in[10];
    const float* p_hard  = (const float*)d_in[11];

    float* X1 = (float*)d_ws;     // chained input, 50.3 MB

    W15 wk;
    {
        double g[15], sum = 0.0;
        for (int i = 0; i < 15; ++i) { double d = (double)(i - 7); g[i] = exp(-d * d / 18.0); sum += g[i]; }
        for (int i = 0; i < 15; ++i) wk.w[i] = (float)(g[i] / sum);
    }

    // K1: x -> X1 (pointwise chain, memory-bound)
    k_point<<<dim3(NTOT / 8 / 256), dim3(256), 0, stream>>>(
        (const vf4*)x, (vf4*)X1, gains, p_gamma, p_sb, p_hr, p_br, p_ct);

    // K2: X1 -> out (double blur + combine + mask)
    dim3 grid(WW / TW, HH / TH, NPLANES);   // 16 x 16 x 12 (remapped in-kernel)
    k_fused<<<grid, dim3(256), 0, stream>>>(
        X1, (float*)d_out, p_enh, p_soft, p_int, p_rot, p_hard, wk);
}

// Round 6
// 179.716 us; speedup vs baseline: 1.1194x; 1.0184x over previous
//
#include <hip/hip_runtime.h>
#include <math.h>

#define HH 1024
#define WW 1024
#define NPLANES 12              // B*C = 4*3
#define PLANE (HH * WW)
#define NTOT (NPLANES * PLANE)

#define TW 64                   // output tile width
#define TH 64                   // output tile height
#define RH 92                   // h1 rows: gy in [y0-14, y0+77]  (phys rows 0..91)
#define RB 78                   // B1/h2 logical rows: gy in [y0-7, y0+70]
#define PH 80                   // pitch (floats), 20 quads, quad-XOR swizzle by (physrow & 3)
// LDS: phys rows 0..91 = h1 (later h2 in rows 0..77); B1 logical rows 0..63 at
// phys rows 92..155; B1 logical rows 64..77 ALIAS h1 phys rows 78..91 (their
// last use is the same P3 iteration that produces the aliasing write).
#define LDSF (156 * PH)         // 49,920 B -> 50,176 alloc -> 3 blocks/CU

typedef float vf4 __attribute__((ext_vector_type(4)));

struct W15 { float w[15]; };

__device__ inline float chain1(float t, float gain, float gamma, float sb,
                               float hr, float br, float ct) {
    t = t * gain;
    t = __builtin_amdgcn_exp2f(gamma * __log2f(t));          // pow(t,gamma), t>=0
    float hi = __fdividef(1.0f, 1.0f + __expf((0.5f - t) * 10.0f));
    t = t + sb * (1.0f - hi) - hr * hi;
    t = fminf(fmaxf(t, 0.0f), 1.0f);
    t = ct * (t - 0.5f) + 0.5f + br;
    return fminf(fmaxf(t, 0.0f), 1.0f);
}

// B1 logical row -> physical LDS row
__device__ inline int b1r(int r) { return (r < 64) ? (92 + r) : (r + 14); }
// swizzled addressing (quad q of phys row pr stored at quad q ^ (pr&3))
__device__ inline int swq(int pr, int q) { return pr * PH + ((q ^ (pr & 3)) << 2); }
__device__ inline int sws(int pr, int j) {
    return pr * PH + ((((j >> 2) ^ (pr & 3)) << 2) | (j & 3));
}

// 16 outputs from a 32-float register window; output j taps f[j+1 .. j+15]
__device__ inline void dot16(const float* f, const W15& wk, float* o) {
#pragma unroll
    for (int j = 0; j < 16; ++j) {
        float a = 0.0f, b = 0.0f;
#pragma unroll
        for (int k = 0; k < 8; ++k)  a += wk.w[k] * f[j + 1 + k];
#pragma unroll
        for (int k = 8; k < 15; ++k) b += wk.w[k] * f[j + 1 + k];
        o[j] = a + b;
    }
}

__device__ inline float dot15(const float* win, const W15& wk) {
    float a = 0.0f, b = 0.0f;
#pragma unroll
    for (int k = 0; k < 8; ++k)  a += wk.w[k] * win[k];
#pragma unroll
    for (int k = 8; k < 15; ++k) b += wk.w[k] * win[k];
    return a + b;
}

// ---- XCD-aware tile remap: same-XCD (mod-8) blocks cover contiguous region ---
__device__ inline void tile_map(int& p, int& x0, int& y0, bool& edge) {
    int L = (blockIdx.z * gridDim.y + blockIdx.y) * gridDim.x + blockIdx.x; // 0..3071
    int xcd = L & 7;
    int t   = L >> 3;
    int g   = xcd * 384 + t;          // contiguous 1.5-plane region per XCD
    p = g >> 8;
    int w  = g & 255;
    int ty = w >> 4, tx = w & 15;
    x0 = tx * TW; y0 = ty * TH;
    edge = (tx == 0) || (tx == 15) || (ty == 0) || (ty == 15);
}

// ============ K1: pointwise chain, x -> x1 ====================================
// 32B/thread; nontemporal loads (x is read-once -> don't evict X1 from L2/L3).
__global__ __launch_bounds__(256) void k_point(
    const vf4* __restrict__ x, vf4* __restrict__ o,
    const float* __restrict__ gains,
    const float* __restrict__ pg, const float* __restrict__ psb,
    const float* __restrict__ phr, const float* __restrict__ pbr,
    const float* __restrict__ pct)
{
    int i = blockIdx.x * blockDim.x + threadIdx.x;   // 0 .. NTOT/8-1
    int c = ((i * 8) / PLANE) % 3;                   // PLANE % 8 == 0 -> uniform
    float gain = gains[c];
    float gamma = *pg, sb = *psb, hr = *phr, br = *pbr, ct = *pct;

    vf4 v0 = __builtin_nontemporal_load(x + 2 * i);
    vf4 v1 = __builtin_nontemporal_load(x + 2 * i + 1);
#pragma unroll
    for (int j = 0; j < 4; ++j) {
        v0[j] = chain1(v0[j], gain, gamma, sb, hr, br, ct);
        v1[j] = chain1(v1[j], gain, gamma, sb, hr, br, ct);
    }
    o[2 * i]     = v0;
    o[2 * i + 1] = v1;
}

// h1-row loader: fills f[32] for unit (r,s); zero-padded on edge tiles
__device__ inline void load_row32(float* f, const float* __restrict__ plane,
                                  int x0, int y0, int r, int s, bool edge) {
    int gy  = y0 - 14 + r;
    int gxa = x0 + 16 * s - 16;              // 16-aligned window base
    if (!edge) {
        const float* rp = plane + (size_t)gy * WW + gxa;
#pragma unroll
        for (int i = 0; i < 8; ++i)
            *(float4*)&f[4 * i] = *(const float4*)(rp + 4 * i);
    } else {
        bool rowin = (unsigned)gy < HH;
        const float* rp = plane + (size_t)(rowin ? gy : 0) * WW;
#pragma unroll
        for (int i = 0; i < 8; ++i) {
            int gq = gxa + 4 * i;
            float4 v = make_float4(0.f, 0.f, 0.f, 0.f);
            if (rowin && gq >= 0 && gq + 3 < WW)   // quads all-in or all-out
                v = *(const float4*)(rp + gq);
            *(float4*)&f[4 * i] = v;
        }
    }
}

// ============ K2: double blur from x1 (global) + combine + mask ===============
__global__ __launch_bounds__(256, 3) void k_fused(
    const float* __restrict__ x1, float* __restrict__ dst,
    const float* __restrict__ penh,
    const float* __restrict__ psoft, const float* __restrict__ pint,
    const float* __restrict__ prot, const float* __restrict__ phard,
    W15 wk)
{
    __shared__ float lds[LDSF];

    int p, x0, y0; bool edge;
    tile_map(p, x0, y0, edge);
    const int tid = threadIdx.x;
    const int tx  = tid & 63;
    const int ty  = tid >> 6;

    const float* __restrict__ plane = x1 + (size_t)p * PLANE;

    // ---------------- P1: h1; software-pipelined (issue all loads first) ------
    float cc[16];
    {
        const int u0 = tid;                  // < 460 always
        const int u1 = tid + 256;
        const bool has1 = (u1 < RH * 5);
        const int r0 = u0 / 5, s0 = u0 - 5 * r0;
        const int r1 = u1 / 5, s1 = u1 - 5 * r1;

        float fA[32], fB[32];
        load_row32(fA, plane, x0, y0, r0, s0, edge);
        if (has1) load_row32(fB, plane, x0, y0, r1, s1, edge);

        // cc loads issued here too; they land during the dot16s below
        const float* pc0 = plane + (size_t)(y0 + ty * 16) * WW + (x0 + tx);
#pragma unroll
        for (int jj = 0; jj < 16; ++jj) cc[jj] = pc0[(size_t)jj * WW];

        float o[16];
        dot16(fA, wk, o);
#pragma unroll
        for (int qq = 0; qq < 4; ++qq)
            *(float4*)&lds[swq(r0, 4 * s0 + qq)] = *(float4*)&o[4 * qq];
        if (has1) {
            dot16(fB, wk, o);
#pragma unroll
            for (int qq = 0; qq < 4; ++qq)
                *(float4*)&lds[swq(r1, 4 * s1 + qq)] = *(float4*)&o[4 * qq];
        }
    }
    __syncthreads();

    // ---------------- P3: B1 = vblur(h1), masked to image support -------------
    // Reads via 4 precomputed base pointers (one per row&3 swizzle variant) so
    // every unrolled access is base + literal offset (ds_read offset:imm).
    if (tid < 240) {
        int j = tid % 80, band = tid / 80;
        int rb0 = band * 26;                 // 0, 26, 52
        bool xin = (unsigned)(x0 - 8 + j) < WW;
        float* bjt[4];
#pragma unroll
        for (int m = 0; m < 4; ++m)
            bjt[m] = lds + rb0 * PH +
                     ((((j >> 2) ^ ((rb0 + m) & 3)) << 2) | (j & 3));
        float win[15];
#pragma unroll
        for (int k = 0; k < 14; ++k) win[k] = bjt[k & 3][k * PH];
#pragma unroll
        for (int jj = 0; jj < 26; ++jj) {
            int t = jj + 14;                 // row rb0+t, t <= 39 (phys <= 91)
            win[14] = bjt[t & 3][t * PH];
            float v = dot15(win, wk);
            if (edge) {
                int gy = y0 - 7 + rb0 + jj;
                if (!((unsigned)gy < HH) || !xin) v = 0.0f;
            }
            lds[sws(b1r(rb0 + jj), j)] = v;  // rl>=64 aliases row just consumed
#pragma unroll
            for (int k = 0; k < 14; ++k) win[k] = win[k + 1];
        }
    }
    __syncthreads();

    // ---------------- P4: h2 = hblur(B1); software-pipelined ------------------
    // (reads phys rows >= 78, writes rows <= 77 -> reorder-safe)
    {
        const int u0 = tid, u1 = tid + 256;
        const bool has1 = (u1 < RB * 4);     // u0 < 312 always
        const int ra = u0 >> 2, sa = u0 & 3;
        const int rb = u1 >> 2, sb2 = u1 & 3;
        const int pa = b1r(ra);

        float fA[32], fB[32];
#pragma unroll
        for (int i = 0; i < 8; ++i)
            *(float4*)&fA[4 * i] = *(const float4*)&lds[swq(pa, 4 * sa + i)];
        if (has1) {
            const int pb = b1r(rb);
#pragma unroll
            for (int i = 0; i < 8; ++i)
                *(float4*)&fB[4 * i] = *(const float4*)&lds[swq(pb, 4 * sb2 + i)];
        }
        float o[16];
        dot16(fA, wk, o);
#pragma unroll
        for (int qq = 0; qq < 4; ++qq)
            *(float4*)&lds[swq(ra, 4 * sa + qq)] = *(float4*)&o[4 * qq];
        if (has1) {
            dot16(fB, wk, o);
#pragma unroll
            for (int qq = 0; qq < 4; ++qq)
                *(float4*)&lds[swq(rb, 4 * sb2 + qq)] = *(float4*)&o[4 * qq];
        }
    }
    __syncthreads();

    // ---------------- P5: B2 = vblur(h2); combine + mask + clip + store -------
    const float e     = *penh;
    const float sf    = *psoft;
    const float inten = *pint;
    const float hard  = *phard;
    const float theta = (*prot) * 0.017453292519943295f;
    const float cth = __cosf(theta), sth = __sinf(theta);
    const int   gx    = x0 + tx;
    const float gbase = (-1.0f + 2.0f * (float)gx * (1.0f / (float)(WW - 1))) * cth;
    const float ce    = 1.0f + e;

    // gradient-mask exp is linear in y -> geometric recurrence (1 exp, 15 muls)
    const float dstep = 2.0f / (float)(HH - 1);
    const float gy0n  = -1.0f + (float)(y0 + ty * 16) * dstep;
    float       E     = __expf(hard * (gbase + gy0n * sth));
    const float q     = __expf(hard * sth * dstep);

    const int ry0 = ty * 16;                 // ry0 & 3 == 0
    float* bwt[4];                           // h2 read bases, variant = row&3
#pragma unroll
    for (int m = 0; m < 4; ++m)
        bwt[m] = lds + ry0 * PH + ((((tx >> 2) ^ m) << 2) | (tx & 3));

    float bb[16];
#pragma unroll
    for (int jj = 0; jj < 16; ++jj)
        bb[jj] = lds[sws(b1r(ry0 + jj + 7), tx + 8)];

    float win[15];
#pragma unroll
    for (int k = 0; k < 14; ++k) win[k] = bwt[k & 3][k * PH];

    float* __restrict__ dstP = dst + (size_t)p * PLANE;
#pragma unroll
    for (int jj = 0; jj < 16; ++jj) {
        int t = jj + 14;                     // row ry0+t, t <= 29
        win[14] = bwt[t & 3][t * PH];
        float B2  = dot15(win, wk);
        float x2c = ce * cc[jj] - e * bb[jj];       // x2 at center
        float bx2 = ce * bb[jj] - e * B2;           // blur(x2) via linearity
        float v   = sf * bx2 + (1.0f - sf) * x2c;
        int   y   = y0 + ry0 + jj;
        float mask = __fdividef(1.0f, 1.0f + E);
        E *= q;
        v = v * (1.0f - inten * mask);
        v = fminf(fmaxf(v, 0.0f), 1.0f);
        __builtin_nontemporal_store(v, &dstP[(size_t)y * WW + gx]);
#pragma unroll
        for (int k = 0; k < 14; ++k) win[k] = win[k + 1];
    }
}

extern "C" void kernel_launch(void* const* d_in, const int* in_sizes, int n_in,
                              void* d_out, int out_size, void* d_ws, size_t ws_size,
                              hipStream_t stream)
{
    const float* x       = (const float*)d_in[0];
    const float* gains   = (const float*)d_in[1];
    const float* p_gamma = (const float*)d_in[2];
    const float* p_sb    = (const float*)d_in[3];
    const float* p_hr    = (const float*)d_in[4];
    const float* p_br    = (const float*)d_in[5];
    const float* p_ct    = (const float*)d_in[6];
    const float* p_enh   = (const float*)d_in[7];
    const float* p_soft  = (const float*)d_in[8];
    const float* p_int   = (const float*)d_in[9];
    const float* p_rot   = (const float*)d_in[10];
    const float* p_hard  = (const float*)d_in[11];

    float* X1 = (float*)d_ws;     // chained input, 50.3 MB

    W15 wk;
    {
        double g[15], sum = 0.0;
        for (int i = 0; i < 15; ++i) { double d = (double)(i - 7); g[i] = exp(-d * d / 18.0); sum += g[i]; }
        for (int i = 0; i < 15; ++i) wk.w[i] = (float)(g[i] / sum);
    }

    // K1: x -> X1 (pointwise chain, memory-bound)
    k_point<<<dim3(NTOT / 8 / 256), dim3(256), 0, stream>>>(
        (const vf4*)x, (vf4*)X1, gains, p_gamma, p_sb, p_hr, p_br, p_ct);

    // K2: X1 -> out (double blur + combine + mask)
    dim3 grid(WW / TW, HH / TH, NPLANES);   // 16 x 16 x 12 (remapped in-kernel)
    k_fused<<<grid, dim3(256), 0, stream>>>(
        X1, (float*)d_out, p_enh, p_soft, p_int, p_rot, p_hard, wk);
}